// Round 3
// baseline (876.832 us; speedup 1.0000x reference)
//
#include <hip/hip_runtime.h>
#include <hip/hip_bf16.h>

// Problem constants (from reference)
#define BB     64
#define NNCH   10000      // N*N channels
#define TT     100
#define TOUT   98         // T - FS + 1
#define FF     16
#define CSPLIT 16         // channel splits per batch
#define CPB    (NNCH / CSPLIT)   // 625 channels per block
#define EPB    (CPB * TT)        // 62500 floats per block chunk
#define VPB    (EPB / 4)         // 15625 float4 per block
#define NITER  ((VPB + 255) / 256)   // 62 full-wave iterations
#define ACCN   (TOUT * FF)       // 1568 accumulators per batch

__global__ __launch_bounds__(256) void tgcnn_scatter(
    const float* __restrict__ x,      // fp32, (B, NN, T) flat
    const float* __restrict__ w,      // fp32, (NN*FS, F) flat = c*48 + dt*16 + f
    const float* __restrict__ gammat, // fp32 scalar
    float* __restrict__ ws)           // fp32 accum (B, TOUT, F)
{
    __shared__ float acc[ACCN];
    const int tid = threadIdx.x;
    const int bid = blockIdx.x;
    const int b   = bid >> 4;
    const int cs  = bid & (CSPLIT - 1);

    for (int i = tid; i < ACCN; i += 256) acc[i] = 0.0f;

    // gamma = 10 * sigmoid(gammat); exp(-g*x) = exp2(kk*x)
    float gt = gammat[0];
    float gamma = 10.0f / (1.0f + __expf(-gt));
    float kk = -gamma * 1.4426950408889634f;

    const int  lane   = tid & 63;
    const int  fl     = lane & 15;      // filter index for this lane
    const int  dtl    = lane >> 4;      // dt (0..2 valid; 3 idle)
    const bool lane48 = (lane < 48);

    const float4* xv = (const float4*)(x + (size_t)b * 1000000u + (size_t)cs * EPB);

    __syncthreads();

    // Fixed trip count + predicated load: every wave stays fully converged
    // at the __ballot/__shfl scatter (VPB % 256 != 0).
    for (int ii = 0; ii < NITER; ++ii) {
        const int it = ii * 256 + tid;
        float4 v = make_float4(0.f, 0.f, 0.f, 0.f);
        if (it < VPB) v = xv[it];
        const float vv[4] = {v.x, v.y, v.z, v.w};
        #pragma unroll
        for (int s = 0; s < 4; ++s) {
            const bool p = (vv[s] != 0.0f);
            float e = 0.0f;
            unsigned pct = 0u;
            if (p) {
                e = exp2f(kk * vv[s]);
                unsigned flat = (unsigned)it * 4u + (unsigned)s; // elem idx in chunk
                unsigned cl   = flat / 100u;                     // local channel
                unsigned tau  = flat - cl * 100u;                // time index
                unsigned cg   = (unsigned)cs * CPB + cl;         // global channel
                pct = ((cg * 48u) << 7) | tau;                   // pack w-row base | tau
            }
            unsigned long long m = __ballot(p);
            while (m) {
                int j = __builtin_ctzll(m);
                m &= (m - 1);
                float    ee  = __shfl(e, j);
                unsigned pj  = (unsigned)__shfl((int)pct, j);
                unsigned tau = pj & 127u;
                float    wv  = w[(pj >> 7) + (unsigned)(lane48 ? lane : 0)];
                int tt = (int)tau - dtl;
                if (lane48 && (unsigned)tt < (unsigned)TOUT)
                    atomicAdd(&acc[tt * 16 + fl], ee * wv);
            }
        }
    }

    __syncthreads();
    float* wsb = ws + (size_t)b * ACCN;
    for (int i = tid; i < ACCN; i += 256) atomicAdd(&wsb[i], acc[i]);
}

__global__ __launch_bounds__(256) void tgcnn_finalize(
    const float* __restrict__ ws, float* __restrict__ out)
{
    int i = blockIdx.x * 256 + threadIdx.x;
    if (i >= BB * FF * TOUT) return;
    int t = i % TOUT;
    int f = (i / TOUT) & (FF - 1);
    int b = i / (FF * TOUT);
    out[i] = ws[(size_t)b * ACCN + t * FF + f];   // fp32 output (reference dtype)
}

extern "C" void kernel_launch(void* const* d_in, const int* in_sizes, int n_in,
                              void* d_out, int out_size, void* d_ws, size_t ws_size,
                              hipStream_t stream) {
    const float* x = (const float*)d_in[0];
    const float* w = (const float*)d_in[1];
    const float* g = (const float*)d_in[2];
    float* ws = (float*)d_ws;

    hipMemsetAsync(d_ws, 0, (size_t)BB * ACCN * sizeof(float), stream);
    tgcnn_scatter<<<BB * CSPLIT, 256, 0, stream>>>(x, w, g, ws);
    tgcnn_finalize<<<(BB * FF * TOUT + 255) / 256, 256, 0, stream>>>(
        ws, (float*)d_out);
}

// Round 4
// 220.379 us; speedup vs baseline: 3.9788x; 3.9788x over previous
//
#include <hip/hip_runtime.h>

// Problem constants
#define BB     64
#define NNCH   10000      // N*N channels
#define TT     100
#define TOUT   98         // T - FS + 1
#define FF     16
#define CSPLIT 25         // channel splits per batch
#define CPB    400        // channels per block (10000/25)
#define G      8          // channels staged per group
#define NGRP   50         // CPB / G
#define ESLD   112        // es row stride (floats), padded (reads up to t0+11=107)
#define WLD    52         // w row stride (floats), padded for 16B-aligned rows
#define ACCN   (TOUT * FF)  // 1568

// Dense formulation: out[b,f,t] = sum_c sum_dt exp(-g*x[b,c,t+dt])[x!=0] * w[c*48+dt*16+f]
// Block = (batch b, channel chunk cs). Stage G=8 exp'd channel rows in LDS once
// (exp amortized over the 48 uses of each element), then 256 threads =
// (8 f-pairs) x (16 t-octets) x (2 channel-halves) register-accumulate.
__global__ __launch_bounds__(256) void tgcnn_dense(
    const float* __restrict__ x,      // (B, NN, T) fp32
    const float* __restrict__ w,      // (NN*FS, F) fp32: c*48 + dt*16 + f
    const float* __restrict__ gammat, // fp32 scalar
    float* __restrict__ ws)           // fp32 accum (B, TOUT, F)
{
    __shared__ float es[G][ESLD];
    __shared__ float wl[G][WLD];

    const int tid = threadIdx.x;
    const int bid = blockIdx.x;
    const int b   = bid / CSPLIT;
    const int cs  = bid % CSPLIT;

    const float gt    = gammat[0];
    const float gamma = 10.0f / (1.0f + __expf(-gt));
    const float kk    = -gamma * 1.4426950408889634f;   // exp(-g*x) = exp2(kk*x)

    const int  fp = tid & 7;          // f-pair index: f = 2*fp, 2*fp+1
    const int  to = (tid >> 3) & 15;  // t-octet: t0 = 8*to
    const int  ch = tid >> 7;         // channel half: cr = ch*4 + k
    const int  f0 = fp * 2;
    const int  t0 = to * 8;
    const bool active = (t0 <= 96);   // to <= 12 produce valid t (< 98)

    float acc0[8], acc1[8];
    #pragma unroll
    for (int i = 0; i < 8; ++i) { acc0[i] = 0.f; acc1[i] = 0.f; }

    // zero-fill es pad columns [100,112) once (never overwritten later)
    if (tid < 24) {
        int cr = tid & 7, j = tid >> 3;
        *(float4*)&es[cr][100 + j * 4] = make_float4(0.f, 0.f, 0.f, 0.f);
    }

    const float4* x4 = (const float4*)x;
    const float4* w4 = (const float4*)w;
    const int cbase = cs * CPB;
    const long long xrow0 = (long long)b * NNCH + cbase;

    const int ld_cr = tid & 7, ld_t4 = tid >> 3;   // stage-x mapping (tid<200): 2-way banks
    const int w_cr  = tid & 7, w_j   = tid >> 3;   // stage-w mapping (tid<96)

    for (int g = 0; g < NGRP; ++g) {
        const int c0 = g * G;
        if (tid < 200) {   // 8 rows x 25 float4
            float4 v = x4[(xrow0 + c0 + ld_cr) * 25 + ld_t4];
            float4 e;
            e.x = (v.x != 0.f) ? exp2f(kk * v.x) : 0.f;
            e.y = (v.y != 0.f) ? exp2f(kk * v.y) : 0.f;
            e.z = (v.z != 0.f) ? exp2f(kk * v.z) : 0.f;
            e.w = (v.w != 0.f) ? exp2f(kk * v.w) : 0.f;
            *(float4*)&es[ld_cr][ld_t4 * 4] = e;
        }
        if (tid < 96) {    // 8 rows x 12 float4 of w
            float4 wv = w4[((long long)(cbase + c0 + w_cr)) * 12 + w_j];
            *(float4*)&wl[w_cr][w_j * 4] = wv;
        }
        __syncthreads();

        if (active) {
            #pragma unroll
            for (int k = 0; k < 4; ++k) {
                const int cr = ch * 4 + k;
                const float4 a0 = *(const float4*)&es[cr][t0];
                const float4 a1 = *(const float4*)&es[cr][t0 + 4];
                const float4 a2 = *(const float4*)&es[cr][t0 + 8];
                const float v[12] = {a0.x, a0.y, a0.z, a0.w,
                                     a1.x, a1.y, a1.z, a1.w,
                                     a2.x, a2.y, a2.z, a2.w};
                const float2 w0 = *(const float2*)&wl[cr][f0];
                const float2 w1 = *(const float2*)&wl[cr][16 + f0];
                const float2 w2 = *(const float2*)&wl[cr][32 + f0];
                #pragma unroll
                for (int i = 0; i < 8; ++i) {
                    acc0[i] += v[i] * w0.x + v[i + 1] * w1.x + v[i + 2] * w2.x;
                    acc1[i] += v[i] * w0.y + v[i + 1] * w1.y + v[i + 2] * w2.y;
                }
            }
        }
        __syncthreads();
    }

    if (active) {
        float* wsb = ws + (size_t)b * ACCN;
        #pragma unroll
        for (int i = 0; i < 8; ++i) {
            const int t = t0 + i;
            if (t < TOUT) {
                atomicAdd(&wsb[t * FF + f0],     acc0[i]);
                atomicAdd(&wsb[t * FF + f0 + 1], acc1[i]);
            }
        }
    }
}

__global__ __launch_bounds__(256) void tgcnn_finalize(
    const float* __restrict__ ws, float* __restrict__ out)
{
    int i = blockIdx.x * 256 + threadIdx.x;
    if (i >= BB * FF * TOUT) return;
    int t = i % TOUT;
    int f = (i / TOUT) & (FF - 1);
    int b = i / (FF * TOUT);
    out[i] = ws[(size_t)b * ACCN + t * FF + f];   // (B,T,F) -> (B,F,1,T)
}

extern "C" void kernel_launch(void* const* d_in, const int* in_sizes, int n_in,
                              void* d_out, int out_size, void* d_ws, size_t ws_size,
                              hipStream_t stream) {
    const float* x = (const float*)d_in[0];
    const float* w = (const float*)d_in[1];
    const float* g = (const float*)d_in[2];
    float* ws = (float*)d_ws;

    hipMemsetAsync(d_ws, 0, (size_t)BB * ACCN * sizeof(float), stream);
    tgcnn_dense<<<BB * CSPLIT, 256, 0, stream>>>(x, w, g, ws);
    tgcnn_finalize<<<(BB * FF * TOUT + 255) / 256, 256, 0, stream>>>(
        ws, (float*)d_out);
}

// Round 5
// 86.472 us; speedup vs baseline: 10.1401x; 2.5486x over previous
//
#include <hip/hip_runtime.h>

// out[b,f,t] = sum_{c,dt} exp(-g*x[b,c,t+dt])[x!=0] * w[c*48+dt*16+f]
// im2col GEMM, M=t (per batch 98), N=f (16), K=(c,dt). MFMA bf16 16x16x32.
#define BB     64
#define NNCH   10000
#define TT     100
#define TOUT   98
#define FF     16
#define CPB    64                 // channels per block
#define NCHUNK 157                // ceil(10000/64)
#define EP     116                // E_raw row pitch (bf16): t 0..113 used, rest zero
#define WP     200                // W row pitch (bf16): k' 0..191
#define ACCN   (TOUT * FF)        // 1568

typedef __attribute__((ext_vector_type(8))) short s8v;   // 8 bf16 (4 VGPRs)
typedef __attribute__((ext_vector_type(4))) float f4v;   // 4 fp32 acc

__device__ __forceinline__ ushort bf_rne(float v) {
    unsigned b = __float_as_uint(v);
    return (ushort)((b + 0x7FFFu + ((b >> 16) & 1u)) >> 16);
}

__global__ __launch_bounds__(256) void tgcnn_mfma(
    const float* __restrict__ x,      // (B, NN, T) fp32
    const float* __restrict__ w,      // (NN*FS, F) fp32: c*48 + dt*16 + f
    const float* __restrict__ gammat, // fp32 scalar
    float* __restrict__ ws)           // fp32 accum (B, TOUT, F)
{
    __shared__ __align__(16) ushort E[CPB][EP];   // E[c][t] bf16, 14848 B
    __shared__ __align__(16) ushort W[FF][WP];    // W[f][k'], k' = dt*64 + c, 6400 B

    const int tid = threadIdx.x;
    const int bid = blockIdx.x;
    const int b   = bid / NCHUNK;
    const int cs  = bid - b * NCHUNK;
    const int cbase = cs * CPB;

    const float gt    = gammat[0];
    const float gamma = 10.0f / (1.0f + __expf(-gt));
    const float kk    = -gamma * 1.4426950408889634f;   // exp(-g*x)=exp2(kk*x)

    // zero LDS (covers t-pad cols 100..115 and tail-chunk rows)
    {
        const uint4 z = make_uint4(0, 0, 0, 0);
        uint4* e4 = (uint4*)&E[0][0];
        for (int i = tid; i < (CPB * EP * 2) / 16; i += 256) e4[i] = z;
        uint4* w4 = (uint4*)&W[0][0];
        for (int i = tid; i < (FF * WP * 2) / 16; i += 256) w4[i] = z;
    }
    __syncthreads();

    // Stage E: coalesced float4 loads (4 t of one c), exp-transform, b64 LDS writes
    const float4* x4 = (const float4*)x;
    for (int i = tid; i < CPB * 25; i += 256) {
        const int cl = i / 25, q = i - cl * 25;
        const int c  = cbase + cl;
        if (c < NNCH) {
            float4 v = x4[((size_t)b * NNCH + c) * 25 + q];
            uint2 p;
            ushort e0 = (v.x != 0.f) ? bf_rne(exp2f(kk * v.x)) : 0;
            ushort e1 = (v.y != 0.f) ? bf_rne(exp2f(kk * v.y)) : 0;
            ushort e2 = (v.z != 0.f) ? bf_rne(exp2f(kk * v.z)) : 0;
            ushort e3 = (v.w != 0.f) ? bf_rne(exp2f(kk * v.w)) : 0;
            p.x = (unsigned)e0 | ((unsigned)e1 << 16);
            p.y = (unsigned)e2 | ((unsigned)e3 << 16);
            *(uint2*)&E[cl][q * 4] = p;   // addr = cl*232 + q*8, 8B-aligned
        }
    }

    // Stage W: w[c*48+dt*16+f] -> W[f][dt*64+cl] bf16
    const float4* wg4 = (const float4*)w;
    for (int i = tid; i < CPB * 12; i += 256) {
        const int cl = i / 12, r = i - cl * 12;
        const int dt = r >> 2, fq = (r & 3) * 4;
        const int c  = cbase + cl;
        if (c < NNCH) {
            float4 wv = wg4[(size_t)c * 12 + r];
            const int kp = dt * CPB + cl;
            W[fq + 0][kp] = bf_rne(wv.x);
            W[fq + 1][kp] = bf_rne(wv.y);
            W[fq + 2][kp] = bf_rne(wv.z);
            W[fq + 3][kp] = bf_rne(wv.w);
        }
    }
    __syncthreads();

    // MFMA: 7 t-tiles (M=112, mask t>=98), wave w owns tiles {w, w+4}
    const int wave = tid >> 6, lane = tid & 63;
    const int tcol = lane & 15;        // A row (t within tile) / D col is f side
    const int kb   = lane >> 4;        // k-octet
    const int f    = lane & 15;        // B col
    const int tile0 = wave, tile1 = wave + 4;

    f4v acc0 = {0.f, 0.f, 0.f, 0.f};
    f4v acc1 = {0.f, 0.f, 0.f, 0.f};

    #pragma unroll
    for (int ks = 0; ks < 6; ++ks) {
        const int dt = ks >> 1;             // k' = ks*32 .. +32 : dt = ks/2
        const int c0 = (ks & 1) * 32;       // c_local base
        const int cb = c0 + kb * 8;

        // B-frag: W[f][ks*32 + kb*8 + j], contiguous -> ds_read_b128
        s8v bfrag = *(const s8v*)&W[f][ks * 32 + kb * 8];

        // A-frag tile0: E[cb+j][tile*16 + tcol + dt], 8 x u16 gather
        {
            const int trow = tile0 * 16 + tcol + dt;
            s8v afrag;
            #pragma unroll
            for (int j = 0; j < 8; ++j) afrag[j] = (short)E[cb + j][trow];
            acc0 = __builtin_amdgcn_mfma_f32_16x16x32_bf16(afrag, bfrag, acc0, 0, 0, 0);
        }
        if (tile1 < 7) {
            const int trow = tile1 * 16 + tcol + dt;
            s8v afrag;
            #pragma unroll
            for (int j = 0; j < 8; ++j) afrag[j] = (short)E[cb + j][trow];
            acc1 = __builtin_amdgcn_mfma_f32_16x16x32_bf16(afrag, bfrag, acc1, 0, 0, 0);
        }
    }

    // C/D layout: col = lane&15 (=f), row = (lane>>4)*4 + r (=t within tile)
    float* wsb = ws + (size_t)b * ACCN;
    const int rbase = (lane >> 4) * 4;
    #pragma unroll
    for (int r = 0; r < 4; ++r) {
        const int m = tile0 * 16 + rbase + r;
        if (m < TOUT) atomicAdd(&wsb[m * FF + f], acc0[r]);
    }
    if (tile1 < 7) {
        #pragma unroll
        for (int r = 0; r < 4; ++r) {
            const int m = tile1 * 16 + rbase + r;
            if (m < TOUT) atomicAdd(&wsb[m * FF + f], acc1[r]);
        }
    }
}

__global__ __launch_bounds__(256) void tgcnn_finalize(
    const float* __restrict__ ws, float* __restrict__ out)
{
    int i = blockIdx.x * 256 + threadIdx.x;
    if (i >= BB * FF * TOUT) return;
    int t = i % TOUT;
    int f = (i / TOUT) & (FF - 1);
    int b = i / (FF * TOUT);
    out[i] = ws[(size_t)b * ACCN + t * FF + f];   // (B,T,F) -> (B,F,1,T)
}

extern "C" void kernel_launch(void* const* d_in, const int* in_sizes, int n_in,
                              void* d_out, int out_size, void* d_ws, size_t ws_size,
                              hipStream_t stream) {
    const float* x = (const float*)d_in[0];
    const float* w = (const float*)d_in[1];
    const float* g = (const float*)d_in[2];
    float* ws = (float*)d_ws;

    hipMemsetAsync(d_ws, 0, (size_t)BB * ACCN * sizeof(float), stream);
    tgcnn_mfma<<<BB * NCHUNK, 256, 0, stream>>>(x, w, g, ws);
    tgcnn_finalize<<<(BB * FF * TOUT + 255) / 256, 256, 0, stream>>>(
        ws, (float*)d_out);
}